// Round 1
// baseline (666.083 us; speedup 1.0000x reference)
//
#include <hip/hip_runtime.h>
#include <math.h>

#define NB 2
#define NS 4096
#define NE 768
#define NH 12
#define ND 64
#define NW 256

// ---------------------------------------------------------------------------
// Kernel 1: fused QKV projection GEMM.
//   out[m,n] = sum_k hs[m,k] * W[n,k] (+ bias), Q scaled by 1/sqrt(64)=0.125.
//   M = B*S = 8192, K = 768, N = 3*768 (n-tile selects which of Q/K/V).
//   Results scattered directly into [B,H,S,D] layout in workspace.
// Tiles: 128x128x16, 256 threads, 8x8 per thread (4+4 split so LDS reads are
// <=2-way bank aliased, which is free on CDNA4).
// ---------------------------------------------------------------------------
__global__ __launch_bounds__(256, 2)
void qkv_proj(const float* __restrict__ hs,
              const float* __restrict__ qw, const float* __restrict__ qb,
              const float* __restrict__ kw, const float* __restrict__ kb,
              const float* __restrict__ vw, const float* __restrict__ vb,
              float* __restrict__ Qo, float* __restrict__ Ko, float* __restrict__ Vo)
{
    __shared__ float As[16][132];   // [k][m], stride 132 floats = 528B (16B mult)
    __shared__ float Bs[16][132];   // [k][n]

    const int t   = threadIdx.x;
    const int bm  = blockIdx.x;          // 0..63   (M tiles)
    const int bn  = blockIdx.y;          // 0..17   (N tiles; 6 per matrix)
    const int mat = bn / 6;              // 0=Q 1=K 2=V
    const int n0  = (bn % 6) * 128;      // column within the matrix

    const float* Wm   = (mat == 0) ? qw : (mat == 1) ? kw : vw;
    const float* bias = (mat == 0) ? qb : (mat == 1) ? kb : vb;
    float*       Out  = (mat == 0) ? Qo : (mat == 1) ? Ko : Vo;
    const float scale = (mat == 0) ? 0.125f : 1.0f;

    const int m0 = bm * 128;
    const int lr = t >> 1;               // 0..127 load row
    const int lk = (t & 1) * 8;          // 0 or 8 load k-offset
    const int tx = t & 15;
    const int ty = t >> 4;

    float acc[8][8];
#pragma unroll
    for (int i = 0; i < 8; ++i)
#pragma unroll
        for (int j = 0; j < 8; ++j) acc[i][j] = 0.f;

    for (int k0 = 0; k0 < NE; k0 += 16) {
        const float* ap = hs + (size_t)(m0 + lr) * NE + (k0 + lk);
        float4 a0 = *(const float4*)(ap);
        float4 a1 = *(const float4*)(ap + 4);
        const float* bp = Wm + (size_t)(n0 + lr) * NE + (k0 + lk);
        float4 b0 = *(const float4*)(bp);
        float4 b1 = *(const float4*)(bp + 4);

        __syncthreads();   // protect previous iteration's LDS reads
        As[lk + 0][lr] = a0.x;  As[lk + 1][lr] = a0.y;
        As[lk + 2][lr] = a0.z;  As[lk + 3][lr] = a0.w;
        As[lk + 4][lr] = a1.x;  As[lk + 5][lr] = a1.y;
        As[lk + 6][lr] = a1.z;  As[lk + 7][lr] = a1.w;
        Bs[lk + 0][lr] = b0.x;  Bs[lk + 1][lr] = b0.y;
        Bs[lk + 2][lr] = b0.z;  Bs[lk + 3][lr] = b0.w;
        Bs[lk + 4][lr] = b1.x;  Bs[lk + 5][lr] = b1.y;
        Bs[lk + 6][lr] = b1.z;  Bs[lk + 7][lr] = b1.w;
        __syncthreads();

#pragma unroll
        for (int kk = 0; kk < 16; ++kk) {
            float4 aa0 = *(const float4*)&As[kk][ty * 4];
            float4 aa1 = *(const float4*)&As[kk][64 + ty * 4];
            float4 bb0 = *(const float4*)&Bs[kk][tx * 4];
            float4 bb1 = *(const float4*)&Bs[kk][64 + tx * 4];
            float a8[8] = {aa0.x, aa0.y, aa0.z, aa0.w, aa1.x, aa1.y, aa1.z, aa1.w};
            float b8[8] = {bb0.x, bb0.y, bb0.z, bb0.w, bb1.x, bb1.y, bb1.z, bb1.w};
#pragma unroll
            for (int i = 0; i < 8; ++i)
#pragma unroll
                for (int j = 0; j < 8; ++j)
                    acc[i][j] = fmaf(a8[i], b8[j], acc[i][j]);
        }
    }

    // epilogue: bias + scale, scatter to [B,H,S,D]
#pragma unroll
    for (int ih = 0; ih < 2; ++ih) {
#pragma unroll
        for (int i = 0; i < 4; ++i) {
            const int m = m0 + ih * 64 + ty * 4 + i;
            const int b = m >> 12;          // m / 4096
            const int s = m & (NS - 1);
#pragma unroll
            for (int jh = 0; jh < 2; ++jh) {
                const int n = n0 + jh * 64 + tx * 4;   // feature index, 4-aligned
                const int h = n >> 6;
                const int d = n & 63;
                float4 r;
                r.x = (acc[ih * 4 + i][jh * 4 + 0] + bias[n + 0]) * scale;
                r.y = (acc[ih * 4 + i][jh * 4 + 1] + bias[n + 1]) * scale;
                r.z = (acc[ih * 4 + i][jh * 4 + 2] + bias[n + 2]) * scale;
                r.w = (acc[ih * 4 + i][jh * 4 + 3] + bias[n + 3]) * scale;
                *(float4*)(Out + (((size_t)(b * NH + h) * NS + s) * ND + d)) = r;
            }
        }
    }
}

// ---------------------------------------------------------------------------
// Kernel 2: sliding-window attention with online softmax.
// One block per (b, h, 64-row q-tile): 2*12*64 = 1536 blocks, 256 threads.
// For each q-tile, loop over the 9 key tiles covering [i0-256, i0+319].
// Key tiles are 64-aligned, so out-of-range tiles are FULLY out of range
// (uniform skip) and the band mask is a clean triangle on kt==0 / kt==8 only.
// LDS: Qt/Kt transposed [d][row] for outer-product scores; P overwrites Kt
// after scores (aliased) to stay under the 64KB static LDS limit.
// ---------------------------------------------------------------------------
__global__ __launch_bounds__(256, 3)
void swattn(const float* __restrict__ Q, const float* __restrict__ K,
            const float* __restrict__ V, float* __restrict__ out)
{
    __shared__ float Qt[ND][68];    // [d][qi]   stride 68 floats = 272B
    __shared__ float Kt[ND][68];    // [d][kj], re-used as Pt[kj][qi]
    __shared__ float Vs[64][68];    // [kj][d]

    float (*Pt)[68] = Kt;

    const int t   = threadIdx.x;
    const int blk = blockIdx.x;
    const int qt  = blk & 63;
    const int bh  = blk >> 6;              // 0..23
    const int i0  = qt * 64;

    const float* Qp = Q + (size_t)bh * NS * ND;
    const float* Kp = K + (size_t)bh * NS * ND;
    const float* Vp = V + (size_t)bh * NS * ND;

    const int lrow = t >> 2;               // 0..63
    const int lseg = (t & 3) * 16;         // 0/16/32/48

    {   // load Q tile transposed (already pre-scaled by 1/8 in qkv_proj)
        const float* qp = Qp + (size_t)(i0 + lrow) * ND + lseg;
#pragma unroll
        for (int x = 0; x < 16; x += 4) {
            float4 v4 = *(const float4*)(qp + x);
            Qt[lseg + x + 0][lrow] = v4.x;
            Qt[lseg + x + 1][lrow] = v4.y;
            Qt[lseg + x + 2][lrow] = v4.z;
            Qt[lseg + x + 3][lrow] = v4.w;
        }
    }

    const int tx = t & 15;                 // key / d-column group
    const int ty = t >> 4;                 // query-row group (0..15)

    float ctx[4][4];
    float m_run[4], l_run[4];
#pragma unroll
    for (int i = 0; i < 4; ++i) {
        m_run[i] = -1e30f;
        l_run[i] = 0.f;
#pragma unroll
        for (int j = 0; j < 4; ++j) ctx[i][j] = 0.f;
    }

    for (int kt = 0; kt < 9; ++kt) {
        const int kj0 = i0 - NW + kt * 64;
        if (kj0 < 0 || kj0 >= NS) continue;   // uniform: tile fully out of range

        __syncthreads();   // previous tile's Pt/Vs reads done before overwrite
        {
            const float* kp = Kp + (size_t)(kj0 + lrow) * ND + lseg;
            const float* vp = Vp + (size_t)(kj0 + lrow) * ND + lseg;
#pragma unroll
            for (int x = 0; x < 16; x += 4) {
                float4 kv = *(const float4*)(kp + x);
                Kt[lseg + x + 0][lrow] = kv.x;
                Kt[lseg + x + 1][lrow] = kv.y;
                Kt[lseg + x + 2][lrow] = kv.z;
                Kt[lseg + x + 3][lrow] = kv.w;
                float4 vv = *(const float4*)(vp + x);
                *(float4*)&Vs[lrow][lseg + x] = vv;
            }
        }
        __syncthreads();

        // ---- scores: s[i][j] = Q[ty*4+i] . K[tx*4+j] ----
        float s[4][4];
#pragma unroll
        for (int i = 0; i < 4; ++i)
#pragma unroll
            for (int j = 0; j < 4; ++j) s[i][j] = 0.f;

#pragma unroll 16
        for (int d = 0; d < ND; ++d) {
            float4 a4 = *(const float4*)&Qt[d][ty * 4];
            float4 b4 = *(const float4*)&Kt[d][tx * 4];
            float av[4] = {a4.x, a4.y, a4.z, a4.w};
            float bv[4] = {b4.x, b4.y, b4.z, b4.w};
#pragma unroll
            for (int i = 0; i < 4; ++i)
#pragma unroll
                for (int j = 0; j < 4; ++j)
                    s[i][j] = fmaf(av[i], bv[j], s[i][j]);
        }

        // ---- band mask (only the extreme tiles need it) ----
        if (kt == 0) {                      // valid iff kj_local >= qi_local
#pragma unroll
            for (int i = 0; i < 4; ++i)
#pragma unroll
                for (int j = 0; j < 4; ++j)
                    if (tx * 4 + j < ty * 4 + i) s[i][j] = -1e30f;
        } else if (kt == 8) {               // valid iff kj_local <= qi_local
#pragma unroll
            for (int i = 0; i < 4; ++i)
#pragma unroll
                for (int j = 0; j < 4; ++j)
                    if (tx * 4 + j > ty * 4 + i) s[i][j] = -1e30f;
        }

        // ---- online softmax (row groups share ty; reduce across 16 tx lanes) ----
        float p[4][4];
#pragma unroll
        for (int i = 0; i < 4; ++i) {
            float v = fmaxf(fmaxf(s[i][0], s[i][1]), fmaxf(s[i][2], s[i][3]));
            v = fmaxf(v, __shfl_xor(v, 1));
            v = fmaxf(v, __shfl_xor(v, 2));
            v = fmaxf(v, __shfl_xor(v, 4));
            v = fmaxf(v, __shfl_xor(v, 8));
            const float mnew = fmaxf(m_run[i], v);
            const float alpha = __expf(m_run[i] - mnew);
            m_run[i] = mnew;
            float sm = 0.f;
#pragma unroll
            for (int j = 0; j < 4; ++j) {
                p[i][j] = __expf(s[i][j] - mnew);
                sm += p[i][j];
            }
            sm += __shfl_xor(sm, 1);
            sm += __shfl_xor(sm, 2);
            sm += __shfl_xor(sm, 4);
            sm += __shfl_xor(sm, 8);
            l_run[i] = l_run[i] * alpha + sm;
#pragma unroll
            for (int j = 0; j < 4; ++j) ctx[i][j] *= alpha;
        }

        __syncthreads();   // all threads done reading Kt before P overwrites it
#pragma unroll
        for (int j = 0; j < 4; ++j) {
            float4 pv = make_float4(p[0][j], p[1][j], p[2][j], p[3][j]);
            *(float4*)&Pt[tx * 4 + j][ty * 4] = pv;
        }
        __syncthreads();

        // ---- PV: ctx[i][dd] += sum_j P[qi][j] * V[j][tx*4+dd] ----
#pragma unroll 16
        for (int j = 0; j < 64; ++j) {
            float4 pp = *(const float4*)&Pt[j][ty * 4];
            float4 vv = *(const float4*)&Vs[j][tx * 4];
            float pa[4] = {pp.x, pp.y, pp.z, pp.w};
#pragma unroll
            for (int i = 0; i < 4; ++i) {
                ctx[i][0] = fmaf(pa[i], vv.x, ctx[i][0]);
                ctx[i][1] = fmaf(pa[i], vv.y, ctx[i][1]);
                ctx[i][2] = fmaf(pa[i], vv.z, ctx[i][2]);
                ctx[i][3] = fmaf(pa[i], vv.w, ctx[i][3]);
            }
        }
    }

    // ---- normalize + write out[b][s][h*64+d] ----
    const int b = bh / NH;
    const int h = bh - b * NH;
    float* op = out + ((size_t)b * NS + i0) * NE + h * ND + tx * 4;
#pragma unroll
    for (int i = 0; i < 4; ++i) {
        const float inv = 1.f / l_run[i];
        float4 r = make_float4(ctx[i][0] * inv, ctx[i][1] * inv,
                               ctx[i][2] * inv, ctx[i][3] * inv);
        *(float4*)(op + (size_t)(ty * 4 + i) * NE) = r;
    }
}

// ---------------------------------------------------------------------------
// Launcher. Workspace layout: Q | K | V in [B,H,S,D] fp32 (25.2 MB each,
// 75.5 MB total — must fit in ws_size).
// ---------------------------------------------------------------------------
extern "C" void kernel_launch(void* const* d_in, const int* in_sizes, int n_in,
                              void* d_out, int out_size, void* d_ws, size_t ws_size,
                              hipStream_t stream) {
    const float* hs = (const float*)d_in[0];
    const float* qw = (const float*)d_in[1];
    const float* qb = (const float*)d_in[2];
    const float* kw = (const float*)d_in[3];
    const float* kb = (const float*)d_in[4];
    const float* vw = (const float*)d_in[5];
    const float* vb = (const float*)d_in[6];
    float* out = (float*)d_out;

    float* Qo = (float*)d_ws;
    float* Ko = Qo + (size_t)NB * NH * NS * ND;
    float* Vo = Ko + (size_t)NB * NH * NS * ND;

    qkv_proj<<<dim3(64, 18), 256, 0, stream>>>(hs, qw, qb, kw, kb, vw, vb, Qo, Ko, Vo);
    swattn<<<dim3(NB * NH * (NS / 64)), 256, 0, stream>>>(Qo, Ko, Vo, out);
}

// Round 2
// 180.494 us; speedup vs baseline: 3.6903x; 3.6903x over previous
//
#include <hip/hip_runtime.h>
#include <math.h>

#define NB 2
#define NS 4096
#define NE 768
#define NH 12
#define ND 64
#define NW 256
#define GK NE

typedef __attribute__((ext_vector_type(8))) short short8v;
typedef __attribute__((ext_vector_type(4))) float f32x4;

__device__ __forceinline__ unsigned short f2bf(float f) {
    unsigned u = __float_as_uint(f);
    u += 0x7FFFu + ((u >> 16) & 1u);
    return (unsigned short)(u >> 16);
}

#if __has_builtin(__builtin_amdgcn_global_load_lds)
#define HAVE_GLL 1
#else
#define HAVE_GLL 0
#endif

// ---------------------------------------------------------------------------
// Kernel 0: fp32 -> bf16 conversion of hidden_states and the three weights.
// Memory-bound (~44 MB); float4 loads, ushort4 stores.
// ---------------------------------------------------------------------------
__global__ __launch_bounds__(256)
void convert_bf16(const float* __restrict__ hs, const float* __restrict__ qw,
                  const float* __restrict__ kw, const float* __restrict__ vw,
                  unsigned short* __restrict__ hsb, unsigned short* __restrict__ Wb)
{
    const int NU_HS = (NB * NS * NE) / 4;     // 1,572,864 float4 units
    const int NU_W  = (NE * NE) / 4;          //   147,456
    const int total = NU_HS + 3 * NU_W;
    for (int u = blockIdx.x * 256 + threadIdx.x; u < total; u += gridDim.x * 256) {
        const float4* src;
        unsigned short* dst;
        if (u < NU_HS) {
            src = (const float4*)hs + u;
            dst = hsb + (size_t)u * 4;
        } else {
            int v = u - NU_HS;
            int m = v / NU_W;
            int r = v - m * NU_W;
            const float* wp = (m == 0) ? qw : (m == 1) ? kw : vw;
            src = (const float4*)wp + r;
            dst = Wb + (size_t)m * (NE * NE) + (size_t)r * 4;
        }
        float4 f = *src;
        ushort4 o;
        o.x = f2bf(f.x); o.y = f2bf(f.y); o.z = f2bf(f.z); o.w = f2bf(f.w);
        *(ushort4*)dst = o;
    }
}

// ---------------------------------------------------------------------------
// Kernel 1: fused QKV projection, bf16 MFMA 16x16x32, fp32 accum.
//   C[m,n] = sum_k hs[m,k] * W[n,k]  (both k-contiguous = gemm_bt layout)
//   128x128 tile, BK=64, 4 waves (2x2 of 64x64), 4x4 frags/wave.
//   Staging: global_load_lds dwordx4 into linear LDS with XOR-16B swizzle
//   applied on the GLOBAL source and on the ds_read (both-sides rule).
//   Q/K use swapped operands (rows=n) so each lane's 4 acc values are 4
//   consecutive features -> one 8B store, full-line after L2 merge.
//   V uses normal orientation (rows=m) and writes V TRANSPOSED [B,H,D,S].
// ---------------------------------------------------------------------------
__global__ __launch_bounds__(256, 2)
void qkv_mfma(const unsigned short* __restrict__ hsb, const unsigned short* __restrict__ Wb,
              const float* __restrict__ qb, const float* __restrict__ kb,
              const float* __restrict__ vb,
              unsigned short* __restrict__ Qg, unsigned short* __restrict__ Kg,
              unsigned short* __restrict__ Vt)
{
    __shared__ unsigned short lA[128 * 64];   // hs tile  [m][k], 16 KB
    __shared__ unsigned short lB[128 * 64];   // W  tile  [n][k], 16 KB

    const int t  = threadIdx.x;
    const int w  = t >> 6;
    const int l  = t & 63;
    const int bm = blockIdx.x;           // 0..63
    const int bn = blockIdx.y;           // 0..17
    const int mat = bn / 6;              // 0=Q 1=K 2=V
    const int n0  = (bn % 6) * 128;
    const int m0  = bm * 128;

    const unsigned short* Wm = Wb + (size_t)mat * (NE * NE);

    // staging geometry: per issue a wave covers 8 rows x 128B
    const int srow = l >> 3;                       // row within 8-group
    const int scol = (((l & 7) ^ srow) << 3);      // swizzled k element offset (x8 bf16)

    // fragment-read geometry
    const int lw   = l & 15;
    const int lk16 = (l >> 4) << 4;                // byte offset of lane's 16B in k
    const int swz  = (l & 7) << 4;                 // read-side XOR (row&7)<<4
    const int r0   = (w >> 1) * 64;
    const int c0   = (w & 1) * 64;

    f32x4 acc[4][4] = {};

    for (int kt = 0; kt < GK / 64; ++kt) {
        const int k0 = kt * 64;
        __syncthreads();
#pragma unroll
        for (int i = 0; i < 4; ++i) {
            const int rowA = m0 + 32 * w + 8 * i + srow;
            const int rowB = n0 + 32 * w + 8 * i + srow;
            const unsigned short* ga = hsb + (size_t)rowA * GK + k0 + scol;
            const unsigned short* gb = Wm  + (size_t)rowB * GK + k0 + scol;
#if HAVE_GLL
            __builtin_amdgcn_global_load_lds(
                (const __attribute__((address_space(1))) void*)ga,
                (__attribute__((address_space(3))) void*)&lA[(32 * w + 8 * i) * 64], 16, 0, 0);
            __builtin_amdgcn_global_load_lds(
                (const __attribute__((address_space(1))) void*)gb,
                (__attribute__((address_space(3))) void*)&lB[(32 * w + 8 * i) * 64], 16, 0, 0);
#else
            *(short8v*)&lA[(32 * w + 8 * i) * 64 + l * 8] = *(const short8v*)ga;
            *(short8v*)&lB[(32 * w + 8 * i) * 64 + l * 8] = *(const short8v*)gb;
#endif
        }
        __syncthreads();

        // role swap: Q/K want rows=n (A from W), V wants rows=m (A from hs)
        const unsigned short* rT = (mat < 2) ? lB : lA;
        const unsigned short* cT = (mat < 2) ? lA : lB;

#pragma unroll
        for (int kk = 0; kk < 2; ++kk) {
            const int pb = (((kk * 64) + lk16) ^ swz) >> 1;   // phys col in shorts
            short8v a[4], b[4];
#pragma unroll
            for (int r = 0; r < 4; ++r)
                a[r] = *(const short8v*)&rT[(r0 + r * 16 + lw) * 64 + pb];
#pragma unroll
            for (int c = 0; c < 4; ++c)
                b[c] = *(const short8v*)&cT[(c0 + c * 16 + lw) * 64 + pb];
#pragma unroll
            for (int r = 0; r < 4; ++r)
#pragma unroll
                for (int c = 0; c < 4; ++c)
                    acc[r][c] = __builtin_amdgcn_mfma_f32_16x16x32_bf16(a[r], b[c], acc[r][c], 0, 0, 0);
        }
    }

    const float* bias = (mat == 0) ? qb : (mat == 1) ? kb : vb;
    const float scale = (mat == 0) ? 0.125f : 1.0f;

    if (mat < 2) {
        unsigned short* Out = (mat == 0) ? Qg : Kg;
#pragma unroll
        for (int r = 0; r < 4; ++r) {
            const int nf0 = n0 + r0 + r * 16 + ((l >> 4) << 2);   // 4 consecutive features
            const float4 b4 = *(const float4*)&bias[nf0];
            const int h  = nf0 >> 6;
            const int d0 = nf0 & 63;
#pragma unroll
            for (int c = 0; c < 4; ++c) {
                const int m  = m0 + c0 + c * 16 + lw;
                const int bb = m >> 12;
                const int s  = m & (NS - 1);
                ushort4 o;
                o.x = f2bf((acc[r][c][0] + b4.x) * scale);
                o.y = f2bf((acc[r][c][1] + b4.y) * scale);
                o.z = f2bf((acc[r][c][2] + b4.z) * scale);
                o.w = f2bf((acc[r][c][3] + b4.w) * scale);
                *(ushort4*)&Out[((size_t)(bb * NH + h) * NS + s) * ND + d0] = o;
            }
        }
    } else {
#pragma unroll
        for (int c = 0; c < 4; ++c) {
            const int nf = n0 + c0 + c * 16 + lw;
            const float bs = bias[nf];
            const int h = nf >> 6;
            const int d = nf & 63;
#pragma unroll
            for (int r = 0; r < 4; ++r) {
                const int m  = m0 + r0 + r * 16 + ((l >> 4) << 2);  // 4 consecutive s
                const int bb = m >> 12;
                const int s0 = m & (NS - 1);
                ushort4 o;
                o.x = f2bf(acc[r][c][0] + bs);
                o.y = f2bf(acc[r][c][1] + bs);
                o.z = f2bf(acc[r][c][2] + bs);
                o.w = f2bf(acc[r][c][3] + bs);
                *(ushort4*)&Vt[((size_t)(bb * NH + h) * ND + d) * NS + s0] = o;
            }
        }
    }
}

// ---------------------------------------------------------------------------
// Kernel 2: sliding-window attention, bf16 MFMA, online softmax.
// Block = (b,h,64-row q-tile), 4 waves, wave w owns q rows 16w..16w+15.
// Q A-frags register-resident (direct global loads). K staged [key][72] bf16,
// V staged from the transposed global as [d][72] bf16 (both 2-way bank alias).
// P goes through a per-wave bf16 LDS buffer (pitch 72) into PV A-frags.
// ---------------------------------------------------------------------------
__global__ __launch_bounds__(256, 3)
void swattn_mfma(const unsigned short* __restrict__ Qg, const unsigned short* __restrict__ Kg,
                 const unsigned short* __restrict__ Vt, float* __restrict__ out)
{
    __shared__ unsigned short Ks[64 * 72];     // [key][d], pitch 72
    __shared__ unsigned short Vs[64 * 72];     // [d][key], pitch 72
    __shared__ unsigned short Ps[4][16 * 72];  // per-wave P [row][key]

    const int t  = threadIdx.x;
    const int w  = t >> 6;
    const int l  = t & 63;
    const int qt = blockIdx.x & 63;
    const int bh = blockIdx.x >> 6;
    const int i0 = qt * 64;

    const unsigned short* Qp = Qg + (size_t)bh * NS * ND;
    const unsigned short* Kp = Kg + (size_t)bh * NS * ND;
    const unsigned short* Vp = Vt + (size_t)bh * ND * NS;

    const int lw = l & 15;
    const int g4 = l >> 4;

    short8v aq[2];
#pragma unroll
    for (int kk = 0; kk < 2; ++kk)
        aq[kk] = *(const short8v*)&Qp[(size_t)(i0 + w * 16 + lw) * ND + kk * 32 + g4 * 8];

    f32x4 cacc[4] = {};           // ctx frags [df]; rows=q, cols=d
    float m_run[4], l_run[4];
#pragma unroll
    for (int j = 0; j < 4; ++j) { m_run[j] = -1e30f; l_run[j] = 0.f; }

    for (int kt = 0; kt < 9; ++kt) {
        const int kj0 = i0 - NW + kt * 64;
        if (kj0 < 0 || kj0 >= NS) continue;   // uniform skip: tile fully OOB

        __syncthreads();
#pragma unroll
        for (int r = 0; r < 2; ++r) {
            const int u   = t + 256 * r;
            const int row = u >> 3;
            const int c8  = (u & 7) * 8;
            *(short8v*)&Ks[row * 72 + c8] = *(const short8v*)&Kp[(size_t)(kj0 + row) * ND + c8];
            *(short8v*)&Vs[row * 72 + c8] = *(const short8v*)&Vp[(size_t)row * NS + kj0 + c8];
        }
        __syncthreads();

        // ---- scores: D[q][key], rows = wave's 16 q, cols = 64 keys ----
        f32x4 sc[4];
#pragma unroll
        for (int cf = 0; cf < 4; ++cf) {
            f32x4 z = {0.f, 0.f, 0.f, 0.f};
#pragma unroll
            for (int kk = 0; kk < 2; ++kk) {
                short8v b = *(const short8v*)&Ks[(cf * 16 + lw) * 72 + kk * 32 + g4 * 8];
                z = __builtin_amdgcn_mfma_f32_16x16x32_bf16(aq[kk], b, z, 0, 0, 0);
            }
            sc[cf] = z;
        }

        // ---- band mask (edge tiles only; clean triangles) ----
        if (kt == 0) {
#pragma unroll
            for (int cf = 0; cf < 4; ++cf) {
                const int lk = cf * 16 + lw;
#pragma unroll
                for (int j = 0; j < 4; ++j)
                    if (lk < w * 16 + g4 * 4 + j) sc[cf][j] = -1e30f;
            }
        } else if (kt == 8) {
#pragma unroll
            for (int cf = 0; cf < 4; ++cf) {
                const int lk = cf * 16 + lw;
#pragma unroll
                for (int j = 0; j < 4; ++j)
                    if (lk > w * 16 + g4 * 4 + j) sc[cf][j] = -1e30f;
            }
        }

        // ---- online softmax; row j held by lanes sharing g4, cols across lw ----
        float p[4][4];
#pragma unroll
        for (int j = 0; j < 4; ++j) {
            float mx = fmaxf(fmaxf(sc[0][j], sc[1][j]), fmaxf(sc[2][j], sc[3][j]));
            mx = fmaxf(mx, __shfl_xor(mx, 1));
            mx = fmaxf(mx, __shfl_xor(mx, 2));
            mx = fmaxf(mx, __shfl_xor(mx, 4));
            mx = fmaxf(mx, __shfl_xor(mx, 8));
            const float mnew  = fmaxf(m_run[j], mx);
            const float alpha = __expf(m_run[j] - mnew);
            m_run[j] = mnew;
            float sm = 0.f;
#pragma unroll
            for (int cf = 0; cf < 4; ++cf) {
                p[cf][j] = __expf(sc[cf][j] - mnew);
                sm += p[cf][j];
            }
            sm += __shfl_xor(sm, 1);
            sm += __shfl_xor(sm, 2);
            sm += __shfl_xor(sm, 4);
            sm += __shfl_xor(sm, 8);
            l_run[j] = l_run[j] * alpha + sm;
#pragma unroll
            for (int df = 0; df < 4; ++df) cacc[df][j] *= alpha;
        }

        // ---- P -> per-wave LDS (bf16), then PV ----
        unsigned short* Pw = Ps[w];
#pragma unroll
        for (int cf = 0; cf < 4; ++cf)
#pragma unroll
            for (int j = 0; j < 4; ++j)
                Pw[(g4 * 4 + j) * 72 + cf * 16 + lw] = f2bf(p[cf][j]);

#pragma unroll
        for (int kk = 0; kk < 2; ++kk) {
            short8v pa = *(const short8v*)&Pw[lw * 72 + kk * 32 + g4 * 8];
#pragma unroll
            for (int df = 0; df < 4; ++df) {
                short8v bv = *(const short8v*)&Vs[(df * 16 + lw) * 72 + kk * 32 + g4 * 8];
                cacc[df] = __builtin_amdgcn_mfma_f32_16x16x32_bf16(pa, bv, cacc[df], 0, 0, 0);
            }
        }
    }

    // ---- normalize + write out[b][s][h*64+d] (fp32) ----
    const int bb = bh / NH;
    const int h  = bh - bb * NH;
#pragma unroll
    for (int j = 0; j < 4; ++j) {
        const float inv = 1.f / l_run[j];
        const int s = i0 + w * 16 + g4 * 4 + j;
        float* op = out + ((size_t)bb * NS + s) * NE + h * ND + lw;
#pragma unroll
        for (int df = 0; df < 4; ++df)
            op[df * 16] = cacc[df][j] * inv;
    }
}

// ---------------------------------------------------------------------------
// Launcher. ws layout (bf16 shorts): hsb | Wb[3] | Q | K | V^T  = 53.9 MB.
// ---------------------------------------------------------------------------
extern "C" void kernel_launch(void* const* d_in, const int* in_sizes, int n_in,
                              void* d_out, int out_size, void* d_ws, size_t ws_size,
                              hipStream_t stream) {
    const float* hs = (const float*)d_in[0];
    const float* qw = (const float*)d_in[1];
    const float* qb = (const float*)d_in[2];
    const float* kw = (const float*)d_in[3];
    const float* kb = (const float*)d_in[4];
    const float* vw = (const float*)d_in[5];
    const float* vb = (const float*)d_in[6];
    float* out = (float*)d_out;

    unsigned short* hsb = (unsigned short*)d_ws;             // 6,291,456
    unsigned short* Wb  = hsb + (size_t)NB * NS * NE;        // 1,769,472
    unsigned short* Qg  = Wb + 3 * NE * NE;                  // 6,291,456
    unsigned short* Kg  = Qg + (size_t)NB * NH * NS * ND;
    unsigned short* Vg  = Kg + (size_t)NB * NH * NS * ND;

    convert_bf16<<<1968, 256, 0, stream>>>(hs, qw, kw, vw, hsb, Wb);
    qkv_mfma<<<dim3(64, 18), 256, 0, stream>>>(hsb, Wb, qb, kb, vb, Qg, Kg, Vg);
    swattn_mfma<<<NB * NH * (NS / 64), 256, 0, stream>>>(Qg, Kg, Vg, out);
}